// Round 13
// baseline (653.137 us; speedup 1.0000x reference)
//
#include <hip/hip_runtime.h>
#include <hip/hip_bf16.h>
#include <math.h>

#define DEV __device__ __forceinline__
using u16 = unsigned short;
typedef __attribute__((ext_vector_type(8))) short bf16x8;
typedef __attribute__((ext_vector_type(4))) float f32x4;

DEV float elu1(float x) { return x > 0.f ? x : expm1f(x); }
DEV float sigm(float x) { return 1.f / (1.f + expf(-x)); }
DEV float b2f(u16 v) { return __uint_as_float((unsigned)v << 16); }
DEV u16 f2b(float x) { __hip_bfloat16 b = __float2bfloat16(x); return *reinterpret_cast<u16*>(&b); }

// ================= CSR build =========================================================
__global__ __launch_bounds__(256) void deg_hist(const int* __restrict__ ei,
                                                int* __restrict__ deg, int E) {
    const int e = blockIdx.x * 256 + threadIdx.x;
    if (e < E) atomicAdd(&deg[ei[E + e]], 1);
}

__global__ __launch_bounds__(256) void scan1(const int* __restrict__ deg,
                                             int* __restrict__ part,
                                             int* __restrict__ bsum, int N) {
    __shared__ int lds[256];
    const int t = threadIdx.x;
    const int base = blockIdx.x * 1024;
    int v[4]; int s = 0;
    #pragma unroll
    for (int k = 0; k < 4; ++k) {
        const int idx = base + t * 4 + k;
        v[k] = (idx < N) ? deg[idx] : 0;
        s += v[k];
    }
    lds[t] = s; __syncthreads();
    int incl = s;
    for (int off = 1; off < 256; off <<= 1) {
        const int add = (t >= off) ? lds[t - off] : 0;
        __syncthreads();
        incl += add; lds[t] = incl;
        __syncthreads();
    }
    if (t == 255) bsum[blockIdx.x] = incl;
    int run = incl - s;
    #pragma unroll
    for (int k = 0; k < 4; ++k) {
        const int idx = base + t * 4 + k;
        if (idx < N) part[idx] = run;
        run += v[k];
    }
}

__global__ __launch_bounds__(256) void scan2(int* __restrict__ bsum, int nb) {
    __shared__ int lds[256];
    __shared__ int carry;
    const int t = threadIdx.x;
    if (t == 0) carry = 0;
    __syncthreads();
    for (int base = 0; base < nb; base += 256) {
        const int idx = base + t;
        const int v = (idx < nb) ? bsum[idx] : 0;
        lds[t] = v; __syncthreads();
        int incl = v;
        for (int off = 1; off < 256; off <<= 1) {
            const int add = (t >= off) ? lds[t - off] : 0;
            __syncthreads();
            incl += add; lds[t] = incl;
            __syncthreads();
        }
        const int c = carry;
        if (idx < nb) bsum[idx] = c + incl - v;
        __syncthreads();
        if (t == 255) carry = c + incl;
        __syncthreads();
    }
}

__global__ __launch_bounds__(256) void scan3(const int* __restrict__ part,
                                             const int* __restrict__ bsum,
                                             int* __restrict__ rowstart,
                                             int* __restrict__ cursor, int N, int E) {
    const int i = blockIdx.x * 256 + threadIdx.x;
    if (i < N) {
        const int v = part[i] + bsum[i >> 10];
        rowstart[i] = v;
        cursor[i] = v;
    }
    if (i == 0) rowstart[N] = E;
}

// scatter edge src + pre-gathered eattr into CSR(dst) order
__global__ __launch_bounds__(256) void edge_scatter(const int* __restrict__ ei,
                                                    const float* __restrict__ eattr,
                                                    int* __restrict__ cursor,
                                                    int* __restrict__ src_s,
                                                    float* __restrict__ eattr_s, int E) {
    const int e = blockIdx.x * 256 + threadIdx.x;
    if (e >= E) return;
    const int src = ei[e], dst = ei[E + e];
    const float2 a0 = *(const float2*)(eattr + (size_t)e * 6);
    const float2 a1 = *(const float2*)(eattr + (size_t)e * 6 + 2);
    const float2 a2 = *(const float2*)(eattr + (size_t)e * 6 + 4);
    const int pos = atomicAdd(&cursor[dst], 1);
    src_s[pos] = src;
    float* ds = eattr_s + (size_t)pos * 6;
    *(float2*)ds = a0; *(float2*)(ds + 2) = a1; *(float2*)(ds + 4) = a2;
}

__global__ __launch_bounds__(256) void build_gstart(const int* __restrict__ batch,
                                                    int* __restrict__ gstart, int N, int B) {
    const int i = blockIdx.x * 256 + threadIdx.x;
    if (i >= N) return;
    const int b = batch[i];
    if (i == 0) for (int g = 0; g <= b; ++g) gstart[g] = 0;
    else {
        const int pb = batch[i - 1];
        for (int g = pb + 1; g <= b; ++g) gstart[g] = i;
    }
    if (i == N - 1) for (int g = b + 1; g <= B; ++g) gstart[g] = N;
}

// ================= weight prep: Wcat=[nn ; nn+l] in B-fragment swizzled order ========
template<int DIN, int DOUT>
__global__ __launch_bounds__(256) void wcat_prep(
    const float* __restrict__ nnW, const float* __restrict__ lW,
    const float* __restrict__ nnB, const float* __restrict__ lB,
    u16* __restrict__ wswz, float* __restrict__ bcomb)
{
    constexpr int COLT = DOUT / 16;
    const int idx = blockIdx.x * 256 + threadIdx.x;
    if (idx < 2 * DIN * DOUT) {
        const int k = idx / DOUT, n = idx % DOUT;
        const float v = (k < DIN) ? nnW[k * DOUT + n]
                                  : nnW[(k - DIN) * DOUT + n] + lW[(k - DIN) * DOUT + n];
        const int kc = k >> 5, khi = (k >> 3) & 3, j = k & 7;
        const int ct = n >> 4, n16 = n & 15;
        wswz[(size_t)(((kc * COLT + ct) * 4 + khi) * 16 + n16) * 8 + j] = f2b(v);
    }
    if (idx < DOUT) bcomb[idx] = nnB[idx] + lB[idx];
}

__global__ __launch_bounds__(256) void f32_to_bf16v(const float* __restrict__ src,
                                                    u16* __restrict__ dst, int n4) {
    const int i = blockIdx.x * 256 + threadIdx.x;
    if (i >= n4) return;
    const float4 v = *(const float4*)(src + (size_t)i * 4);
    ushort4 u; u.x = f2b(v.x); u.y = f2b(v.y); u.z = f2b(v.z); u.w = f2b(v.w);
    *(ushort4*)(dst + (size_t)i * 4) = u;
}

// ================= fused layer: gather (-> LDS) + MFMA + coalesced store =============
// Block = 64 nodes, 1024 threads (16 waves).  Round-7 gather instruction stream
// (4-wide ILP groups + serial tail), 4 nodes per wave; 16-wave phase-B mapping:
// wave w -> col-tile w%COLT, node-group base (w/COLT)*NGW, NGW = 4*COLT/16.
template<int DIN, int DOUT, bool ELU, typename TOUT>
__global__ __launch_bounds__(1024) void fused_layer(
    const float* __restrict__ xf, const u16* __restrict__ hb,
    const float* __restrict__ eattr_s, const float* __restrict__ ew, const float* __restrict__ eb,
    const int* __restrict__ rowstart, const int* __restrict__ src_s,
    const u16* __restrict__ wswz, const float* __restrict__ bcomb,
    TOUT* __restrict__ out, int N)
{
    constexpr int KC1  = DIN / 32;
    constexpr int KC_TOT = 2 * KC1;
    constexpr int COLT = DOUT / 16;            // 8 or 4
    constexpr int NGW  = (COLT == 8) ? 2 : 1;  // node-groups (of 16) per wave
    constexpr int ASTR = (DIN == 32) ? 80 : 272;
    __shared__ char ldsb[64 * 272];
    const int tid = threadIdx.x;
    const int nb  = blockIdx.x * 64;

    // -------- phase A: gather aggr tile into LDS --------
    if constexpr (DIN == 32) {
        const int j = tid & 31;
        const int slot = tid >> 5;             // 0..31
        #pragma unroll
        for (int it = 0; it < 2; ++it) {
            const int nl = it * 32 + slot;
            const int n = nb + nl;
            if (n < N) {
                const int s0 = rowstart[n], s1 = rowstart[n + 1];
                const float w0 = ew[j], w1 = ew[32 + j], w2 = ew[64 + j],
                            w3 = ew[96 + j], w4 = ew[128 + j], w5 = ew[160 + j];
                const float bj = eb[j];
                float accA = 0.f, accB = 0.f;
                int k = s0;
                for (; k + 4 <= s1; k += 4) {
                    int sr[4];
                    #pragma unroll
                    for (int u = 0; u < 4; ++u) sr[u] = src_s[k + u];
                    float xv[4]; float2 ea[4][3];
                    #pragma unroll
                    for (int u = 0; u < 4; ++u) {
                        xv[u] = xf[(size_t)sr[u] * 32 + j];
                        const float* ep = eattr_s + (size_t)(k + u) * 6;
                        ea[u][0] = *(const float2*)ep;
                        ea[u][1] = *(const float2*)(ep + 2);
                        ea[u][2] = *(const float2*)(ep + 4);
                    }
                    #pragma unroll
                    for (int u = 0; u < 4; ++u) {
                        float el = bj;
                        el = fmaf(ea[u][0].x, w0, el); el = fmaf(ea[u][0].y, w1, el);
                        el = fmaf(ea[u][1].x, w2, el); el = fmaf(ea[u][1].y, w3, el);
                        el = fmaf(ea[u][2].x, w4, el); el = fmaf(ea[u][2].y, w5, el);
                        const float m = fmaxf(xv[u] + el, 0.f);
                        if (u & 1) accB += m; else accA += m;
                    }
                }
                for (; k < s1; ++k) {
                    const int sr = src_s[k];
                    const float* ep = eattr_s + (size_t)k * 6;
                    float el = bj;
                    el = fmaf(ep[0], w0, el); el = fmaf(ep[1], w1, el);
                    el = fmaf(ep[2], w2, el); el = fmaf(ep[3], w3, el);
                    el = fmaf(ep[4], w4, el); el = fmaf(ep[5], w5, el);
                    accA += fmaxf(xf[(size_t)sr * 32 + j] + el, 0.f);
                }
                *(u16*)(ldsb + nl * 80 + j * 2) = f2b(accA + accB);
            }
        }
    } else {
        const int lane = tid & 63;
        const int wid  = tid >> 6;             // 0..15
        const int j0 = lane << 1;
        float2 wv[6];
        #pragma unroll
        for (int q = 0; q < 6; ++q) wv[q] = *(const float2*)(ew + q * 128 + j0);
        const float2 bv = *(const float2*)(eb + j0);
        for (int it = 0; it < 4; ++it) {
            const int n = __builtin_amdgcn_readfirstlane(nb + it * 16 + wid);
            const int nl = n - nb;
            if (n < N) {
                const int s0 = rowstart[n], s1 = rowstart[n + 1];
                float a0A = 0.f, a1A = 0.f, a0B = 0.f, a1B = 0.f;
                int k = s0;
                for (; k + 4 <= s1; k += 4) {
                    int sr[4];
                    #pragma unroll
                    for (int u = 0; u < 4; ++u) sr[u] = src_s[k + u];
                    ushort2 xv[4];
                    #pragma unroll
                    for (int u = 0; u < 4; ++u)
                        xv[u] = *(const ushort2*)(hb + (size_t)sr[u] * 128 + j0);
                    #pragma unroll
                    for (int u = 0; u < 4; ++u) {
                        const float* ep = eattr_s + (size_t)(k + u) * 6;
                        const float e0 = ep[0], e1 = ep[1], e2 = ep[2],
                                    e3 = ep[3], e4 = ep[4], e5 = ep[5];
                        float l0 = bv.x, l1 = bv.y;
                        l0 = fmaf(e0, wv[0].x, l0); l1 = fmaf(e0, wv[0].y, l1);
                        l0 = fmaf(e1, wv[1].x, l0); l1 = fmaf(e1, wv[1].y, l1);
                        l0 = fmaf(e2, wv[2].x, l0); l1 = fmaf(e2, wv[2].y, l1);
                        l0 = fmaf(e3, wv[3].x, l0); l1 = fmaf(e3, wv[3].y, l1);
                        l0 = fmaf(e4, wv[4].x, l0); l1 = fmaf(e4, wv[4].y, l1);
                        l0 = fmaf(e5, wv[5].x, l0); l1 = fmaf(e5, wv[5].y, l1);
                        const float m0 = fmaxf(b2f(xv[u].x) + l0, 0.f);
                        const float m1 = fmaxf(b2f(xv[u].y) + l1, 0.f);
                        if (u & 1) { a0B += m0; a1B += m1; } else { a0A += m0; a1A += m1; }
                    }
                }
                for (; k < s1; ++k) {
                    const int sr = src_s[k];
                    const ushort2 xv = *(const ushort2*)(hb + (size_t)sr * 128 + j0);
                    const float* ep = eattr_s + (size_t)k * 6;
                    float l0 = bv.x, l1 = bv.y;
                    l0 = fmaf(ep[0], wv[0].x, l0); l1 = fmaf(ep[0], wv[0].y, l1);
                    l0 = fmaf(ep[1], wv[1].x, l0); l1 = fmaf(ep[1], wv[1].y, l1);
                    l0 = fmaf(ep[2], wv[2].x, l0); l1 = fmaf(ep[2], wv[2].y, l1);
                    l0 = fmaf(ep[3], wv[3].x, l0); l1 = fmaf(ep[3], wv[3].y, l1);
                    l0 = fmaf(ep[4], wv[4].x, l0); l1 = fmaf(ep[4], wv[4].y, l1);
                    l0 = fmaf(ep[5], wv[5].x, l0); l1 = fmaf(ep[5], wv[5].y, l1);
                    a0A += fmaxf(b2f(xv.x) + l0, 0.f);
                    a1A += fmaxf(b2f(xv.y) + l1, 0.f);
                }
                ushort2 o; o.x = f2b(a0A + a0B); o.y = f2b(a1A + a1B);
                *(ushort2*)(ldsb + nl * 272 + j0 * 2) = o;
            }
        }
    }
    __syncthreads();

    // -------- phase B: MFMA (wave w: col-tile w%COLT, node-groups gbase..gbase+NGW-1) --
    const int lane = tid & 63, wid = tid >> 6;
    const int n16 = lane & 15, khi = lane >> 4;
    const int ct = wid % COLT;
    const int gbase = (wid / COLT) * NGW;
    f32x4 acc[NGW];
    #pragma unroll
    for (int gi = 0; gi < NGW; ++gi) acc[gi] = (f32x4){0.f, 0.f, 0.f, 0.f};
    #pragma unroll
    for (int kc = 0; kc < KC_TOT; ++kc) {
        const bf16x8 bf = *(const bf16x8*)(wswz + (size_t)(((kc * COLT + ct) * 4 + khi) * 16 + n16) * 8);
        #pragma unroll
        for (int gi = 0; gi < NGW; ++gi) {
            const int g = gbase + gi;
            bf16x8 af;
            if (kc < KC1) {
                af = *(const bf16x8*)(ldsb + (g * 16 + n16) * ASTR + kc * 64 + khi * 16);
            } else {
                const int row = min(nb + g * 16 + n16, N - 1);
                af = *(const bf16x8*)(hb + (size_t)row * DIN + (kc - KC1) * 32 + khi * 8);
            }
            acc[gi] = __builtin_amdgcn_mfma_f32_16x16x32_bf16(af, bf, acc[gi], 0, 0, 0);
        }
    }
    __syncthreads();

    // -------- epilogue: C -> LDS, then coalesced float4 stores --------
    {
        const int col = ct * 16 + n16;
        const float bv = bcomb[col];
        #pragma unroll
        for (int gi = 0; gi < NGW; ++gi) {
            const int g = gbase + gi;
            #pragma unroll
            for (int r = 0; r < 4; ++r) {
                const int nl = g * 16 + khi * 4 + r;
                float v = acc[gi][r] + bv;
                if (ELU) v = elu1(v);
                if constexpr (sizeof(TOUT) == 2) *(u16*)(ldsb + nl * 272 + col * 2) = f2b(v);
                else                             *(float*)(ldsb + nl * 272 + col * 4) = v;
            }
        }
    }
    __syncthreads();
    char* outc = (char*)out;
    {
        const int row = tid >> 4, cch = tid & 15;     // 64 rows x 16 chunks = 1024 tasks
        if (nb + row < N)
            *(float4*)(outc + (size_t)(nb + row) * (DOUT * sizeof(TOUT)) + cch * 16) =
                *(const float4*)(ldsb + row * 272 + cch * 16);
    }
}

// ================= set2set (round-7 verified version) ================================
__global__ __launch_bounds__(256) void lstm_gates(
    const float* __restrict__ qstar, const float* __restrict__ hS,
    const float* __restrict__ wih, const float* __restrict__ whh,
    const float* __restrict__ bih, const float* __restrict__ bhh,
    float* __restrict__ gates, int B)
{
    const int idx = blockIdx.x * 256 + threadIdx.x;
    const int g = idx >> 8, jj = idx & 255;
    if (g >= B) return;
    float acc = bih[jj] + bhh[jj];
    const float* q = qstar + g * 128;
    const float* h = hS + g * 64;
    #pragma unroll 4
    for (int k = 0; k < 128; ++k) acc = fmaf(q[k], wih[k * 256 + jj], acc);
    #pragma unroll 4
    for (int k = 0; k < 64;  ++k) acc = fmaf(h[k], whh[k * 256 + jj], acc);
    gates[g * 256 + jj] = acc;
}

__global__ __launch_bounds__(256) void lstm_update(
    const float* __restrict__ gates, float* __restrict__ cS, float* __restrict__ hS, int B)
{
    const int idx = blockIdx.x * 256 + threadIdx.x;
    const int g = idx >> 6, d = idx & 63;
    if (g >= B) return;
    const float i_ = gates[g * 256 + d];
    const float f_ = gates[g * 256 + 64 + d];
    const float g_ = gates[g * 256 + 128 + d];
    const float o_ = gates[g * 256 + 192 + d];
    float c = cS[g * 64 + d];
    c = sigm(f_) * c + sigm(i_) * tanhf(g_);
    cS[g * 64 + d] = c;
    hS[g * 64 + d] = sigm(o_) * tanhf(c);
}

__global__ __launch_bounds__(256) void attn_step(
    const float* __restrict__ h3, const float* __restrict__ hS,
    const int* __restrict__ gstart, float* __restrict__ qstar, int B)
{
    const int g = (blockIdx.x * 256 + threadIdx.x) >> 6;
    const int lane = threadIdx.x & 63;
    if (g >= B) return;
    const float q = hS[g * 64 + lane];
    const int s0 = gstart[g], s1 = gstart[g + 1];
    float m = -INFINITY, ssum = 0.f, racc = 0.f;
    int n = s0;
    for (; n + 2 <= s1; n += 2) {
        const float hv0 = h3[(size_t)n * 64 + lane];
        const float hv1 = h3[(size_t)(n + 1) * 64 + lane];
        float v0 = hv0 * q, v1 = hv1 * q;
        #pragma unroll
        for (int off = 32; off; off >>= 1) {
            v0 += __shfl_xor(v0, off, 64);
            v1 += __shfl_xor(v1, off, 64);
        }
        const float mnew = fmaxf(m, fmaxf(v0, v1));
        const float sc = expf(m - mnew);
        const float a0 = expf(v0 - mnew);
        const float a1 = expf(v1 - mnew);
        ssum = ssum * sc + a0 + a1;
        racc = racc * sc + a0 * hv0 + a1 * hv1;
        m = mnew;
    }
    for (; n < s1; ++n) {
        const float hv = h3[(size_t)n * 64 + lane];
        float v = hv * q;
        #pragma unroll
        for (int off = 32; off; off >>= 1) v += __shfl_xor(v, off, 64);
        const float mnew = fmaxf(m, v);
        const float sc = expf(m - mnew);
        const float a  = expf(v - mnew);
        ssum = ssum * sc + a;
        racc = racc * sc + a * hv;
        m = mnew;
    }
    const float r = (ssum > 0.f) ? racc / ssum : 0.f;
    qstar[g * 128 + lane] = q;
    qstar[g * 128 + 64 + lane] = r;
}

// ================= head ==============================================================
__global__ __launch_bounds__(256) void mlp_hidden(
    const float* __restrict__ qstar, const float* __restrict__ t, const float* __restrict__ p,
    const float* __restrict__ l4w, const float* __restrict__ l4b,
    float* __restrict__ hidden, int B)
{
    const int idx = blockIdx.x * 256 + threadIdx.x;
    const int g = idx >> 7, j = idx & 127;
    if (g >= B) return;
    float acc = l4b[j];
    const float* q = qstar + (size_t)g * 128;
    #pragma unroll 4
    for (int k = 0; k < 128; ++k) acc = fmaf(q[k], l4w[k * 128 + j], acc);
    acc = fmaf(t[g], l4w[128 * 128 + j], acc);
    acc = fmaf(p[g], l4w[129 * 128 + j], acc);
    hidden[(size_t)g * 128 + j] = fmaxf(acc, 0.f);
}

__global__ __launch_bounds__(256) void out_proj(
    const float* __restrict__ hidden, const float* __restrict__ l5w,
    const float* __restrict__ l5b, float* __restrict__ dout, int B)
{
    const int wid = (blockIdx.x * 256 + threadIdx.x) >> 6;
    const int lane = threadIdx.x & 63;
    if (wid >= B) return;
    float s = fmaf(hidden[(size_t)wid * 128 + lane], l5w[lane],
                   hidden[(size_t)wid * 128 + 64 + lane] * l5w[64 + lane]);
    #pragma unroll
    for (int m = 32; m; m >>= 1) s += __shfl_xor(s, m, 64);
    if (lane == 0) dout[wid] = s + l5b[0];
}

// ================= launch ============================================================
extern "C" void kernel_launch(void* const* d_in, const int* in_sizes, int n_in,
                              void* d_out, int out_size, void* d_ws, size_t ws_size,
                              hipStream_t stream)
{
    const float* x     = (const float*)d_in[0];
    const float* eattr = (const float*)d_in[1];
    const float* t     = (const float*)d_in[2];
    const float* p     = (const float*)d_in[3];
    const float* e1w = (const float*)d_in[4];  const float* e1b = (const float*)d_in[5];
    const float* nn1w= (const float*)d_in[6];  const float* nn1b= (const float*)d_in[7];
    const float* l1w = (const float*)d_in[8];  const float* l1b = (const float*)d_in[9];
    const float* e2w = (const float*)d_in[10]; const float* e2b = (const float*)d_in[11];
    const float* nn2w= (const float*)d_in[12]; const float* nn2b= (const float*)d_in[13];
    const float* l2w = (const float*)d_in[14]; const float* l2b = (const float*)d_in[15];
    const float* e3w = (const float*)d_in[16]; const float* e3b = (const float*)d_in[17];
    const float* nn3w= (const float*)d_in[18]; const float* nn3b= (const float*)d_in[19];
    const float* l3w = (const float*)d_in[20]; const float* l3b = (const float*)d_in[21];
    const float* wih = (const float*)d_in[22]; const float* whh = (const float*)d_in[23];
    const float* bih = (const float*)d_in[24]; const float* bhh = (const float*)d_in[25];
    const float* l4w = (const float*)d_in[26]; const float* l4b = (const float*)d_in[27];
    const float* l5w = (const float*)d_in[28]; const float* l5b = (const float*)d_in[29];
    const int* ei    = (const int*)d_in[30];
    const int* batch = (const int*)d_in[31];
    float* dout = (float*)d_out;

    const int N = in_sizes[0] / 32;
    const int E = in_sizes[30] / 2;
    const int B = in_sizes[2];

    // ---- workspace layout ----
    char* basep = (char*)d_ws;
    size_t off = 0;
    auto take = [&](size_t bytes) -> char* {
        char* ptr = basep + off;
        off = (off + bytes + 255) & ~(size_t)255;
        return ptr;
    };
    int* src_s      = (int*)  take((size_t)E * 4);
    float* eattr_s  = (float*)take((size_t)E * 24);
    int* deg      = (int*) take((size_t)N * 4);
    int* part     = (int*) take((size_t)N * 4);
    int* bsum     = (int*) take(4096);
    int* rowstart = (int*) take((size_t)(N + 1) * 4);
    int* cursor   = (int*) take((size_t)N * 4);
    int* gstart   = (int*) take((size_t)(B + 1) * 4);
    u16* h1       = (u16*) take((size_t)N * 128 * 2);
    u16* h2       = (u16*) take((size_t)N * 128 * 2);
    float* h3     = (float*)h1;                          // overlays h1 (dead by then)
    u16* xb       = (u16*) take((size_t)N * 32 * 2);
    u16* w1swz    = (u16*) take((size_t)2 * 32 * 128 * 2);
    u16* w2swz    = (u16*) take((size_t)2 * 128 * 128 * 2);
    u16* w3swz    = (u16*) take((size_t)2 * 128 * 64 * 2);
    float* b1c    = (float*)take(128 * 4);
    float* b2c    = (float*)take(128 * 4);
    float* b3c    = (float*)take(64 * 4);
    float* hS     = (float*)take((size_t)B * 256 * 4);   // hS|cS|qstar contiguous
    float* cS     = hS + (size_t)B * 64;
    float* qstar  = cS + (size_t)B * 64;
    float* gates  = (float*)take((size_t)B * 256 * 4);
    float* hidden = (float*)take((size_t)B * 128 * 4);
    (void)ws_size;

    // ---- CSR build + graph segments + preps ----
    hipMemsetAsync(deg, 0, (size_t)N * 4, stream);
    deg_hist<<<(E + 255) / 256, 256, 0, stream>>>(ei, deg, E);
    const int NB1 = (N + 1023) / 1024;
    scan1<<<NB1, 256, 0, stream>>>(deg, part, bsum, N);
    scan2<<<1, 256, 0, stream>>>(bsum, NB1);
    scan3<<<(N + 255) / 256, 256, 0, stream>>>(part, bsum, rowstart, cursor, N, E);
    edge_scatter<<<(E + 255) / 256, 256, 0, stream>>>(ei, eattr, cursor, src_s, eattr_s, E);
    build_gstart<<<(N + 255) / 256, 256, 0, stream>>>(batch, gstart, N, B);
    f32_to_bf16v<<<(N * 8 + 255) / 256, 256, 0, stream>>>(x, xb, N * 8);
    wcat_prep<32, 128><<<(2 * 32 * 128 + 255) / 256, 256, 0, stream>>>(nn1w, l1w, nn1b, l1b, w1swz, b1c);
    wcat_prep<128, 128><<<(2 * 128 * 128 + 255) / 256, 256, 0, stream>>>(nn2w, l2w, nn2b, l2b, w2swz, b2c);
    wcat_prep<128, 64><<<(2 * 128 * 64 + 255) / 256, 256, 0, stream>>>(nn3w, l3w, nn3b, l3b, w3swz, b3c);

    const int FB = (N + 63) / 64;
    fused_layer<32, 128, true, u16><<<FB, 1024, 0, stream>>>(
        x, xb, eattr_s, e1w, e1b, rowstart, src_s, w1swz, b1c, h1, N);
    fused_layer<128, 128, true, u16><<<FB, 1024, 0, stream>>>(
        nullptr, h1, eattr_s, e2w, e2b, rowstart, src_s, w2swz, b2c, h2, N);
    fused_layer<128, 64, false, float><<<FB, 1024, 0, stream>>>(
        nullptr, h2, eattr_s, e3w, e3b, rowstart, src_s, w3swz, b3c, h3, N);

    // ---- set2set (3 steps) ----
    hipMemsetAsync(hS, 0, (size_t)B * 256 * 4, stream);   // hS, cS, qstar
    for (int step = 0; step < 3; ++step) {
        lstm_gates<<<(B * 256 + 255) / 256, 256, 0, stream>>>(qstar, hS, wih, whh, bih, bhh, gates, B);
        lstm_update<<<(B * 64 + 255) / 256, 256, 0, stream>>>(gates, cS, hS, B);
        attn_step<<<(B * 64 + 255) / 256, 256, 0, stream>>>(h3, hS, gstart, qstar, B);
    }

    // ---- head ----
    mlp_hidden<<<(B * 128 + 255) / 256, 256, 0, stream>>>(qstar, t, p, l4w, l4b, hidden, B);
    out_proj<<<(B * 64 + 255) / 256, 256, 0, stream>>>(hidden, l5w, l5b, dout, B);
}

// Round 14
// 605.468 us; speedup vs baseline: 1.0787x; 1.0787x over previous
//
#include <hip/hip_runtime.h>
#include <hip/hip_bf16.h>
#include <math.h>

#define DEV __device__ __forceinline__
using u16 = unsigned short;
typedef __attribute__((ext_vector_type(8))) short bf16x8;
typedef __attribute__((ext_vector_type(4))) float f32x4;

DEV float elu1(float x) { return x > 0.f ? x : expm1f(x); }
DEV float sigm(float x) { return 1.f / (1.f + expf(-x)); }
DEV float b2f(u16 v) { return __uint_as_float((unsigned)v << 16); }
DEV u16 f2b(float x) { __hip_bfloat16 b = __float2bfloat16(x); return *reinterpret_cast<u16*>(&b); }

// ================= CSR build =========================================================
__global__ __launch_bounds__(256) void deg_hist(const int* __restrict__ ei,
                                                int* __restrict__ deg, int E) {
    const int e = blockIdx.x * 256 + threadIdx.x;
    if (e < E) atomicAdd(&deg[ei[E + e]], 1);
}

__global__ __launch_bounds__(256) void scan1(const int* __restrict__ deg,
                                             int* __restrict__ part,
                                             int* __restrict__ bsum, int N) {
    __shared__ int lds[256];
    const int t = threadIdx.x;
    const int base = blockIdx.x * 1024;
    int v[4]; int s = 0;
    #pragma unroll
    for (int k = 0; k < 4; ++k) {
        const int idx = base + t * 4 + k;
        v[k] = (idx < N) ? deg[idx] : 0;
        s += v[k];
    }
    lds[t] = s; __syncthreads();
    int incl = s;
    for (int off = 1; off < 256; off <<= 1) {
        const int add = (t >= off) ? lds[t - off] : 0;
        __syncthreads();
        incl += add; lds[t] = incl;
        __syncthreads();
    }
    if (t == 255) bsum[blockIdx.x] = incl;
    int run = incl - s;
    #pragma unroll
    for (int k = 0; k < 4; ++k) {
        const int idx = base + t * 4 + k;
        if (idx < N) part[idx] = run;
        run += v[k];
    }
}

__global__ __launch_bounds__(256) void scan2(int* __restrict__ bsum, int nb) {
    __shared__ int lds[256];
    __shared__ int carry;
    const int t = threadIdx.x;
    if (t == 0) carry = 0;
    __syncthreads();
    for (int base = 0; base < nb; base += 256) {
        const int idx = base + t;
        const int v = (idx < nb) ? bsum[idx] : 0;
        lds[t] = v; __syncthreads();
        int incl = v;
        for (int off = 1; off < 256; off <<= 1) {
            const int add = (t >= off) ? lds[t - off] : 0;
            __syncthreads();
            incl += add; lds[t] = incl;
            __syncthreads();
        }
        const int c = carry;
        if (idx < nb) bsum[idx] = c + incl - v;
        __syncthreads();
        if (t == 255) carry = c + incl;
        __syncthreads();
    }
}

__global__ __launch_bounds__(256) void scan3(const int* __restrict__ part,
                                             const int* __restrict__ bsum,
                                             int* __restrict__ rowstart,
                                             int* __restrict__ cursor, int N, int E) {
    const int i = blockIdx.x * 256 + threadIdx.x;
    if (i < N) {
        const int v = part[i] + bsum[i >> 10];
        rowstart[i] = v;
        cursor[i] = v;
    }
    if (i == 0) rowstart[N] = E;
}

// scatter edge src + pre-gathered eattr into CSR(dst) order
__global__ __launch_bounds__(256) void edge_scatter(const int* __restrict__ ei,
                                                    const float* __restrict__ eattr,
                                                    int* __restrict__ cursor,
                                                    int* __restrict__ src_s,
                                                    float* __restrict__ eattr_s, int E) {
    const int e = blockIdx.x * 256 + threadIdx.x;
    if (e >= E) return;
    const int src = ei[e], dst = ei[E + e];
    const float2 a0 = *(const float2*)(eattr + (size_t)e * 6);
    const float2 a1 = *(const float2*)(eattr + (size_t)e * 6 + 2);
    const float2 a2 = *(const float2*)(eattr + (size_t)e * 6 + 4);
    const int pos = atomicAdd(&cursor[dst], 1);
    src_s[pos] = src;
    float* ds = eattr_s + (size_t)pos * 6;
    *(float2*)ds = a0; *(float2*)(ds + 2) = a1; *(float2*)(ds + 4) = a2;
}

__global__ __launch_bounds__(256) void build_gstart(const int* __restrict__ batch,
                                                    int* __restrict__ gstart, int N, int B) {
    const int i = blockIdx.x * 256 + threadIdx.x;
    if (i >= N) return;
    const int b = batch[i];
    if (i == 0) for (int g = 0; g <= b; ++g) gstart[g] = 0;
    else {
        const int pb = batch[i - 1];
        for (int g = pb + 1; g <= b; ++g) gstart[g] = i;
    }
    if (i == N - 1) for (int g = b + 1; g <= B; ++g) gstart[g] = N;
}

// ================= weight prep: Wcat=[nn ; nn+l] in B-fragment swizzled order ========
template<int DIN, int DOUT>
__global__ __launch_bounds__(256) void wcat_prep(
    const float* __restrict__ nnW, const float* __restrict__ lW,
    const float* __restrict__ nnB, const float* __restrict__ lB,
    u16* __restrict__ wswz, float* __restrict__ bcomb)
{
    constexpr int COLT = DOUT / 16;
    const int idx = blockIdx.x * 256 + threadIdx.x;
    if (idx < 2 * DIN * DOUT) {
        const int k = idx / DOUT, n = idx % DOUT;
        const float v = (k < DIN) ? nnW[k * DOUT + n]
                                  : nnW[(k - DIN) * DOUT + n] + lW[(k - DIN) * DOUT + n];
        const int kc = k >> 5, khi = (k >> 3) & 3, j = k & 7;
        const int ct = n >> 4, n16 = n & 15;
        wswz[(size_t)(((kc * COLT + ct) * 4 + khi) * 16 + n16) * 8 + j] = f2b(v);
    }
    if (idx < DOUT) bcomb[idx] = nnB[idx] + lB[idx];
}

__global__ __launch_bounds__(256) void f32_to_bf16v(const float* __restrict__ src,
                                                    u16* __restrict__ dst, int n4) {
    const int i = blockIdx.x * 256 + threadIdx.x;
    if (i >= n4) return;
    const float4 v = *(const float4*)(src + (size_t)i * 4);
    ushort4 u; u.x = f2b(v.x); u.y = f2b(v.y); u.z = f2b(v.z); u.w = f2b(v.w);
    *(ushort4*)(dst + (size_t)i * 4) = u;
}

// ================= fused layer: gather (-> LDS) + MFMA + coalesced store =============
// Block = 64 nodes, 512 threads (8 waves).  Round-7 gather instruction stream
// (4-wide ILP groups + serial tail), but 8 nodes per wave (half the serial chain)
// and 8-wave phase-B mapping: wave w -> col-tile w%COLT, node-group base (w/COLT)*NGW.
template<int DIN, int DOUT, bool ELU, typename TOUT>
__global__ __launch_bounds__(512) void fused_layer(
    const float* __restrict__ xf, const u16* __restrict__ hb,
    const float* __restrict__ eattr_s, const float* __restrict__ ew, const float* __restrict__ eb,
    const int* __restrict__ rowstart, const int* __restrict__ src_s,
    const u16* __restrict__ wswz, const float* __restrict__ bcomb,
    TOUT* __restrict__ out, int N)
{
    constexpr int KC1  = DIN / 32;
    constexpr int KC_TOT = 2 * KC1;
    constexpr int COLT = DOUT / 16;          // 8 or 4
    constexpr int NGW  = (COLT == 8) ? 4 : 2; // node-groups (of 16) per wave
    constexpr int ASTR = (DIN == 32) ? 80 : 272;
    __shared__ char ldsb[64 * 272];
    const int tid = threadIdx.x;
    const int nb  = blockIdx.x * 64;

    // -------- phase A: gather aggr tile into LDS --------
    if constexpr (DIN == 32) {
        const int j = tid & 31;
        const int slot = tid >> 5;            // 0..15
        #pragma unroll 2
        for (int it = 0; it < 4; ++it) {
            const int nl = it * 16 + slot;
            const int n = nb + nl;
            if (n < N) {
                const int s0 = rowstart[n], s1 = rowstart[n + 1];
                const float w0 = ew[j], w1 = ew[32 + j], w2 = ew[64 + j],
                            w3 = ew[96 + j], w4 = ew[128 + j], w5 = ew[160 + j];
                const float bj = eb[j];
                float accA = 0.f, accB = 0.f;
                int k = s0;
                for (; k + 4 <= s1; k += 4) {
                    int sr[4];
                    #pragma unroll
                    for (int u = 0; u < 4; ++u) sr[u] = src_s[k + u];
                    float xv[4]; float2 ea[4][3];
                    #pragma unroll
                    for (int u = 0; u < 4; ++u) {
                        xv[u] = xf[(size_t)sr[u] * 32 + j];
                        const float* ep = eattr_s + (size_t)(k + u) * 6;
                        ea[u][0] = *(const float2*)ep;
                        ea[u][1] = *(const float2*)(ep + 2);
                        ea[u][2] = *(const float2*)(ep + 4);
                    }
                    #pragma unroll
                    for (int u = 0; u < 4; ++u) {
                        float el = bj;
                        el = fmaf(ea[u][0].x, w0, el); el = fmaf(ea[u][0].y, w1, el);
                        el = fmaf(ea[u][1].x, w2, el); el = fmaf(ea[u][1].y, w3, el);
                        el = fmaf(ea[u][2].x, w4, el); el = fmaf(ea[u][2].y, w5, el);
                        const float m = fmaxf(xv[u] + el, 0.f);
                        if (u & 1) accB += m; else accA += m;
                    }
                }
                for (; k < s1; ++k) {
                    const int sr = src_s[k];
                    const float* ep = eattr_s + (size_t)k * 6;
                    float el = bj;
                    el = fmaf(ep[0], w0, el); el = fmaf(ep[1], w1, el);
                    el = fmaf(ep[2], w2, el); el = fmaf(ep[3], w3, el);
                    el = fmaf(ep[4], w4, el); el = fmaf(ep[5], w5, el);
                    accA += fmaxf(xf[(size_t)sr * 32 + j] + el, 0.f);
                }
                *(u16*)(ldsb + nl * 80 + j * 2) = f2b(accA + accB);
            }
        }
    } else {
        const int lane = tid & 63;
        const int wid  = tid >> 6;            // 0..7
        const int j0 = lane << 1;
        float2 wv[6];
        #pragma unroll
        for (int q = 0; q < 6; ++q) wv[q] = *(const float2*)(ew + q * 128 + j0);
        const float2 bv = *(const float2*)(eb + j0);
        for (int it = 0; it < 8; ++it) {
            const int n = __builtin_amdgcn_readfirstlane(nb + it * 8 + wid);
            const int nl = n - nb;
            if (n < N) {
                const int s0 = rowstart[n], s1 = rowstart[n + 1];
                float a0A = 0.f, a1A = 0.f, a0B = 0.f, a1B = 0.f;
                int k = s0;
                for (; k + 4 <= s1; k += 4) {
                    int sr[4];
                    #pragma unroll
                    for (int u = 0; u < 4; ++u) sr[u] = src_s[k + u];
                    ushort2 xv[4];
                    #pragma unroll
                    for (int u = 0; u < 4; ++u)
                        xv[u] = *(const ushort2*)(hb + (size_t)sr[u] * 128 + j0);
                    #pragma unroll
                    for (int u = 0; u < 4; ++u) {
                        const float* ep = eattr_s + (size_t)(k + u) * 6;
                        const float e0 = ep[0], e1 = ep[1], e2 = ep[2],
                                    e3 = ep[3], e4 = ep[4], e5 = ep[5];
                        float l0 = bv.x, l1 = bv.y;
                        l0 = fmaf(e0, wv[0].x, l0); l1 = fmaf(e0, wv[0].y, l1);
                        l0 = fmaf(e1, wv[1].x, l0); l1 = fmaf(e1, wv[1].y, l1);
                        l0 = fmaf(e2, wv[2].x, l0); l1 = fmaf(e2, wv[2].y, l1);
                        l0 = fmaf(e3, wv[3].x, l0); l1 = fmaf(e3, wv[3].y, l1);
                        l0 = fmaf(e4, wv[4].x, l0); l1 = fmaf(e4, wv[4].y, l1);
                        l0 = fmaf(e5, wv[5].x, l0); l1 = fmaf(e5, wv[5].y, l1);
                        const float m0 = fmaxf(b2f(xv[u].x) + l0, 0.f);
                        const float m1 = fmaxf(b2f(xv[u].y) + l1, 0.f);
                        if (u & 1) { a0B += m0; a1B += m1; } else { a0A += m0; a1A += m1; }
                    }
                }
                for (; k < s1; ++k) {
                    const int sr = src_s[k];
                    const ushort2 xv = *(const ushort2*)(hb + (size_t)sr * 128 + j0);
                    const float* ep = eattr_s + (size_t)k * 6;
                    float l0 = bv.x, l1 = bv.y;
                    l0 = fmaf(ep[0], wv[0].x, l0); l1 = fmaf(ep[0], wv[0].y, l1);
                    l0 = fmaf(ep[1], wv[1].x, l0); l1 = fmaf(ep[1], wv[1].y, l1);
                    l0 = fmaf(ep[2], wv[2].x, l0); l1 = fmaf(ep[2], wv[2].y, l1);
                    l0 = fmaf(ep[3], wv[3].x, l0); l1 = fmaf(ep[3], wv[3].y, l1);
                    l0 = fmaf(ep[4], wv[4].x, l0); l1 = fmaf(ep[4], wv[4].y, l1);
                    l0 = fmaf(ep[5], wv[5].x, l0); l1 = fmaf(ep[5], wv[5].y, l1);
                    a0A += fmaxf(b2f(xv.x) + l0, 0.f);
                    a1A += fmaxf(b2f(xv.y) + l1, 0.f);
                }
                ushort2 o; o.x = f2b(a0A + a0B); o.y = f2b(a1A + a1B);
                *(ushort2*)(ldsb + nl * 272 + j0 * 2) = o;
            }
        }
    }
    __syncthreads();

    // -------- phase B: MFMA (wave w: col-tile w%COLT, node-groups gbase..gbase+NGW-1) --
    const int lane = tid & 63, wid = tid >> 6;
    const int n16 = lane & 15, khi = lane >> 4;
    const int ct = wid % COLT;
    const int gbase = (wid / COLT) * NGW;
    f32x4 acc[NGW];
    #pragma unroll
    for (int gi = 0; gi < NGW; ++gi) acc[gi] = (f32x4){0.f, 0.f, 0.f, 0.f};
    #pragma unroll
    for (int kc = 0; kc < KC_TOT; ++kc) {
        const bf16x8 bf = *(const bf16x8*)(wswz + (size_t)(((kc * COLT + ct) * 4 + khi) * 16 + n16) * 8);
        #pragma unroll
        for (int gi = 0; gi < NGW; ++gi) {
            const int g = gbase + gi;
            bf16x8 af;
            if (kc < KC1) {
                af = *(const bf16x8*)(ldsb + (g * 16 + n16) * ASTR + kc * 64 + khi * 16);
            } else {
                const int row = min(nb + g * 16 + n16, N - 1);
                af = *(const bf16x8*)(hb + (size_t)row * DIN + (kc - KC1) * 32 + khi * 8);
            }
            acc[gi] = __builtin_amdgcn_mfma_f32_16x16x32_bf16(af, bf, acc[gi], 0, 0, 0);
        }
    }
    __syncthreads();

    // -------- epilogue: C -> LDS, then coalesced float4 stores --------
    {
        const int col = ct * 16 + n16;
        const float bv = bcomb[col];
        #pragma unroll
        for (int gi = 0; gi < NGW; ++gi) {
            const int g = gbase + gi;
            #pragma unroll
            for (int r = 0; r < 4; ++r) {
                const int nl = g * 16 + khi * 4 + r;
                float v = acc[gi][r] + bv;
                if (ELU) v = elu1(v);
                if constexpr (sizeof(TOUT) == 2) *(u16*)(ldsb + nl * 272 + col * 2) = f2b(v);
                else                             *(float*)(ldsb + nl * 272 + col * 4) = v;
            }
        }
    }
    __syncthreads();
    char* outc = (char*)out;
    #pragma unroll
    for (int it = 0; it < 2; ++it) {
        const int task = it * 512 + tid;
        const int row = task >> 4, cch = task & 15;   // 16 chunks x 16B = 256B/row
        if (nb + row < N)
            *(float4*)(outc + (size_t)(nb + row) * (DOUT * sizeof(TOUT)) + cch * 16) =
                *(const float4*)(ldsb + row * 272 + cch * 16);
    }
}

// ================= set2set (round-7 verified version) ================================
__global__ __launch_bounds__(256) void lstm_gates(
    const float* __restrict__ qstar, const float* __restrict__ hS,
    const float* __restrict__ wih, const float* __restrict__ whh,
    const float* __restrict__ bih, const float* __restrict__ bhh,
    float* __restrict__ gates, int B)
{
    const int idx = blockIdx.x * 256 + threadIdx.x;
    const int g = idx >> 8, jj = idx & 255;
    if (g >= B) return;
    float acc = bih[jj] + bhh[jj];
    const float* q = qstar + g * 128;
    const float* h = hS + g * 64;
    #pragma unroll 4
    for (int k = 0; k < 128; ++k) acc = fmaf(q[k], wih[k * 256 + jj], acc);
    #pragma unroll 4
    for (int k = 0; k < 64;  ++k) acc = fmaf(h[k], whh[k * 256 + jj], acc);
    gates[g * 256 + jj] = acc;
}

__global__ __launch_bounds__(256) void lstm_update(
    const float* __restrict__ gates, float* __restrict__ cS, float* __restrict__ hS, int B)
{
    const int idx = blockIdx.x * 256 + threadIdx.x;
    const int g = idx >> 6, d = idx & 63;
    if (g >= B) return;
    const float i_ = gates[g * 256 + d];
    const float f_ = gates[g * 256 + 64 + d];
    const float g_ = gates[g * 256 + 128 + d];
    const float o_ = gates[g * 256 + 192 + d];
    float c = cS[g * 64 + d];
    c = sigm(f_) * c + sigm(i_) * tanhf(g_);
    cS[g * 64 + d] = c;
    hS[g * 64 + d] = sigm(o_) * tanhf(c);
}

__global__ __launch_bounds__(256) void attn_step(
    const float* __restrict__ h3, const float* __restrict__ hS,
    const int* __restrict__ gstart, float* __restrict__ qstar, int B)
{
    const int g = (blockIdx.x * 256 + threadIdx.x) >> 6;
    const int lane = threadIdx.x & 63;
    if (g >= B) return;
    const float q = hS[g * 64 + lane];
    const int s0 = gstart[g], s1 = gstart[g + 1];
    float m = -INFINITY, ssum = 0.f, racc = 0.f;
    int n = s0;
    for (; n + 2 <= s1; n += 2) {
        const float hv0 = h3[(size_t)n * 64 + lane];
        const float hv1 = h3[(size_t)(n + 1) * 64 + lane];
        float v0 = hv0 * q, v1 = hv1 * q;
        #pragma unroll
        for (int off = 32; off; off >>= 1) {
            v0 += __shfl_xor(v0, off, 64);
            v1 += __shfl_xor(v1, off, 64);
        }
        const float mnew = fmaxf(m, fmaxf(v0, v1));
        const float sc = expf(m - mnew);
        const float a0 = expf(v0 - mnew);
        const float a1 = expf(v1 - mnew);
        ssum = ssum * sc + a0 + a1;
        racc = racc * sc + a0 * hv0 + a1 * hv1;
        m = mnew;
    }
    for (; n < s1; ++n) {
        const float hv = h3[(size_t)n * 64 + lane];
        float v = hv * q;
        #pragma unroll
        for (int off = 32; off; off >>= 1) v += __shfl_xor(v, off, 64);
        const float mnew = fmaxf(m, v);
        const float sc = expf(m - mnew);
        const float a  = expf(v - mnew);
        ssum = ssum * sc + a;
        racc = racc * sc + a * hv;
        m = mnew;
    }
    const float r = (ssum > 0.f) ? racc / ssum : 0.f;
    qstar[g * 128 + lane] = q;
    qstar[g * 128 + 64 + lane] = r;
}

// ================= head ==============================================================
__global__ __launch_bounds__(256) void mlp_hidden(
    const float* __restrict__ qstar, const float* __restrict__ t, const float* __restrict__ p,
    const float* __restrict__ l4w, const float* __restrict__ l4b,
    float* __restrict__ hidden, int B)
{
    const int idx = blockIdx.x * 256 + threadIdx.x;
    const int g = idx >> 7, j = idx & 127;
    if (g >= B) return;
    float acc = l4b[j];
    const float* q = qstar + (size_t)g * 128;
    #pragma unroll 4
    for (int k = 0; k < 128; ++k) acc = fmaf(q[k], l4w[k * 128 + j], acc);
    acc = fmaf(t[g], l4w[128 * 128 + j], acc);
    acc = fmaf(p[g], l4w[129 * 128 + j], acc);
    hidden[(size_t)g * 128 + j] = fmaxf(acc, 0.f);
}

__global__ __launch_bounds__(256) void out_proj(
    const float* __restrict__ hidden, const float* __restrict__ l5w,
    const float* __restrict__ l5b, float* __restrict__ dout, int B)
{
    const int wid = (blockIdx.x * 256 + threadIdx.x) >> 6;
    const int lane = threadIdx.x & 63;
    if (wid >= B) return;
    float s = fmaf(hidden[(size_t)wid * 128 + lane], l5w[lane],
                   hidden[(size_t)wid * 128 + 64 + lane] * l5w[64 + lane]);
    #pragma unroll
    for (int m = 32; m; m >>= 1) s += __shfl_xor(s, m, 64);
    if (lane == 0) dout[wid] = s + l5b[0];
}

// ================= launch ============================================================
extern "C" void kernel_launch(void* const* d_in, const int* in_sizes, int n_in,
                              void* d_out, int out_size, void* d_ws, size_t ws_size,
                              hipStream_t stream)
{
    const float* x     = (const float*)d_in[0];
    const float* eattr = (const float*)d_in[1];
    const float* t     = (const float*)d_in[2];
    const float* p     = (const float*)d_in[3];
    const float* e1w = (const float*)d_in[4];  const float* e1b = (const float*)d_in[5];
    const float* nn1w= (const float*)d_in[6];  const float* nn1b= (const float*)d_in[7];
    const float* l1w = (const float*)d_in[8];  const float* l1b = (const float*)d_in[9];
    const float* e2w = (const float*)d_in[10]; const float* e2b = (const float*)d_in[11];
    const float* nn2w= (const float*)d_in[12]; const float* nn2b= (const float*)d_in[13];
    const float* l2w = (const float*)d_in[14]; const float* l2b = (const float*)d_in[15];
    const float* e3w = (const float*)d_in[16]; const float* e3b = (const float*)d_in[17];
    const float* nn3w= (const float*)d_in[18]; const float* nn3b= (const float*)d_in[19];
    const float* l3w = (const float*)d_in[20]; const float* l3b = (const float*)d_in[21];
    const float* wih = (const float*)d_in[22]; const float* whh = (const float*)d_in[23];
    const float* bih = (const float*)d_in[24]; const float* bhh = (const float*)d_in[25];
    const float* l4w = (const float*)d_in[26]; const float* l4b = (const float*)d_in[27];
    const float* l5w = (const float*)d_in[28]; const float* l5b = (const float*)d_in[29];
    const int* ei    = (const int*)d_in[30];
    const int* batch = (const int*)d_in[31];
    float* dout = (float*)d_out;

    const int N = in_sizes[0] / 32;
    const int E = in_sizes[30] / 2;
    const int B = in_sizes[2];

    // ---- workspace layout ----
    char* basep = (char*)d_ws;
    size_t off = 0;
    auto take = [&](size_t bytes) -> char* {
        char* ptr = basep + off;
        off = (off + bytes + 255) & ~(size_t)255;
        return ptr;
    };
    int* src_s      = (int*)  take((size_t)E * 4);
    float* eattr_s  = (float*)take((size_t)E * 24);
    int* deg      = (int*) take((size_t)N * 4);
    int* part     = (int*) take((size_t)N * 4);
    int* bsum     = (int*) take(4096);
    int* rowstart = (int*) take((size_t)(N + 1) * 4);
    int* cursor   = (int*) take((size_t)N * 4);
    int* gstart   = (int*) take((size_t)(B + 1) * 4);
    u16* h1       = (u16*) take((size_t)N * 128 * 2);
    u16* h2       = (u16*) take((size_t)N * 128 * 2);
    float* h3     = (float*)h1;                          // overlays h1 (dead by then)
    u16* xb       = (u16*) take((size_t)N * 32 * 2);
    u16* w1swz    = (u16*) take((size_t)2 * 32 * 128 * 2);
    u16* w2swz    = (u16*) take((size_t)2 * 128 * 128 * 2);
    u16* w3swz    = (u16*) take((size_t)2 * 128 * 64 * 2);
    float* b1c    = (float*)take(128 * 4);
    float* b2c    = (float*)take(128 * 4);
    float* b3c    = (float*)take(64 * 4);
    float* hS     = (float*)take((size_t)B * 256 * 4);   // hS|cS|qstar contiguous
    float* cS     = hS + (size_t)B * 64;
    float* qstar  = cS + (size_t)B * 64;
    float* gates  = (float*)take((size_t)B * 256 * 4);
    float* hidden = (float*)take((size_t)B * 128 * 4);
    (void)ws_size;

    // ---- CSR build + graph segments + preps ----
    hipMemsetAsync(deg, 0, (size_t)N * 4, stream);
    deg_hist<<<(E + 255) / 256, 256, 0, stream>>>(ei, deg, E);
    const int NB1 = (N + 1023) / 1024;
    scan1<<<NB1, 256, 0, stream>>>(deg, part, bsum, N);
    scan2<<<1, 256, 0, stream>>>(bsum, NB1);
    scan3<<<(N + 255) / 256, 256, 0, stream>>>(part, bsum, rowstart, cursor, N, E);
    edge_scatter<<<(E + 255) / 256, 256, 0, stream>>>(ei, eattr, cursor, src_s, eattr_s, E);
    build_gstart<<<(N + 255) / 256, 256, 0, stream>>>(batch, gstart, N, B);
    f32_to_bf16v<<<(N * 8 + 255) / 256, 256, 0, stream>>>(x, xb, N * 8);
    wcat_prep<32, 128><<<(2 * 32 * 128 + 255) / 256, 256, 0, stream>>>(nn1w, l1w, nn1b, l1b, w1swz, b1c);
    wcat_prep<128, 128><<<(2 * 128 * 128 + 255) / 256, 256, 0, stream>>>(nn2w, l2w, nn2b, l2b, w2swz, b2c);
    wcat_prep<128, 64><<<(2 * 128 * 64 + 255) / 256, 256, 0, stream>>>(nn3w, l3w, nn3b, l3b, w3swz, b3c);

    const int FB = (N + 63) / 64;
    fused_layer<32, 128, true, u16><<<FB, 512, 0, stream>>>(
        x, xb, eattr_s, e1w, e1b, rowstart, src_s, w1swz, b1c, h1, N);
    fused_layer<128, 128, true, u16><<<FB, 512, 0, stream>>>(
        nullptr, h1, eattr_s, e2w, e2b, rowstart, src_s, w2swz, b2c, h2, N);
    fused_layer<128, 64, false, float><<<FB, 512, 0, stream>>>(
        nullptr, h2, eattr_s, e3w, e3b, rowstart, src_s, w3swz, b3c, h3, N);

    // ---- set2set (3 steps) ----
    hipMemsetAsync(hS, 0, (size_t)B * 256 * 4, stream);   // hS, cS, qstar
    for (int step = 0; step < 3; ++step) {
        lstm_gates<<<(B * 256 + 255) / 256, 256, 0, stream>>>(qstar, hS, wih, whh, bih, bhh, gates, B);
        lstm_update<<<(B * 64 + 255) / 256, 256, 0, stream>>>(gates, cS, hS, B);
        attn_step<<<(B * 64 + 255) / 256, 256, 0, stream>>>(h3, hS, gstart, qstar, B);
    }

    // ---- head ----
    mlp_hidden<<<(B * 128 + 255) / 256, 256, 0, stream>>>(qstar, t, p, l4w, l4b, hidden, B);
    out_proj<<<(B * 64 + 255) / 256, 256, 0, stream>>>(hidden, l5w, l5b, dout, B);
}